// Round 5
// baseline (451.927 us; speedup 1.0000x reference)
//
#include <hip/hip_runtime.h>
#include <hip/hip_fp16.h>
#include <math.h>

#define THREADS 256
#define RPB 32
#define NBLK (65536 / RPB)   // 2048 blocks

// ---- workspace layout (float offsets) ----
// W1 pair-layout images: 16 chunks (32 k each) of 2048 floats:
//   chunk[it]: off = p*64 + (m ^ (p&15))*4 + kb*2 + j  (p=col-pair 0..31,
//   m=k-pair-in-chunk 0..15, kb=k low bit, j=col low bit)
//   holds W1[c=2p+j][k=it*32+2m+kb].  One b128 = 2 k x 2 cols; XOR spreads banks.
// W2 images: 4 chunks of 128 cols, 8192 floats each, pre-XOR-swizzled (R1 layout)
// W1 last column (epsilon weights): 64 floats
#define WS_W1    0
#define WS_W1_CH 2048
#define WS_W2    (16 * WS_W1_CH)          // 32768
#define WS_W2_CH 8192
#define WS_W1L   (WS_W2 + 4 * WS_W2_CH)   // 65536
// total 65600 floats = 262400 bytes of d_ws

// ---- LDS layout (bytes) ----
// 45824 B/block -> 3 blocks/CU (LDS-capped; measured R1/R4: occupancy lever is
// exhausted at 3 blocks - the DS pipe is the bottleneck, so minimize ds_reads).
// TOOLCHAIN GOTCHA (R1-R4 measured): __launch_bounds__(256,N) budgets VGPRs
// for 2N waves/EU (512/2N) and spills to reach it: N=3->85, N=4->64+spill,
// N=5->48+spill. Use N=2 (budget 128): zero spill risk; residency LDS-capped.
#define OFF_W    0
#define W1BUF_B  8192                     // 2048 floats per W1 chunk
#define SZ_W     32768                    // union: W1 dbuf 2x8192 | W2 chunk 32768
#define OFF_H1   (OFF_W + SZ_W)           // 32768
#define SZ_H1    (RPB * 68 * 4)           // 8704
#define OFF_CI   (OFF_H1 + SZ_H1)         // 41472
#define SZ_CI    2048
#define OFF_B2   (OFF_CI + SZ_CI)         // 43520
#define SZ_B2    2048
#define OFF_EPS  (OFF_B2 + SZ_B2)         // 45568
#define OFF_EPSC (OFF_EPS + 128)          // 45696
#define SMEM_BYTES (OFF_EPSC + 128)       // 45824

__device__ __forceinline__ float fast_tanh(float z) {
    // tanh(z) = 1 - 2/(e^{2z}+1); saturates correctly for |z| large (inf/0 paths)
    float e = __expf(2.0f * z);
    return fmaf(-2.0f, __builtin_amdgcn_rcpf(e + 1.0f), 1.0f);
}

// ---------------- prep: materialize LDS images of weights in ws ----------------
__global__ __launch_bounds__(256) void prep_kernel(
    const float* __restrict__ W1, const float* __restrict__ W2,
    float* __restrict__ ws)
{
    int tid = blockIdx.x * 256 + threadIdx.x;   // 0..32767, grid = 128 blocks
    // W1 pair-layout chunk images
    {
        int it = tid >> 11;            // 0..15
        int rem = tid & 2047;
        int j  = rem & 1;              // col low bit
        int kb = (rem >> 1) & 1;       // k low bit
        int m  = (rem >> 2) & 15;      // k pair index in chunk
        int p  = rem >> 6;             // col pair 0..31
        int off = it * WS_W1_CH + p * 64 + ((m ^ (p & 15)) << 2) + kb * 2 + j;
        ws[WS_W1 + off] = W1[(2 * p + j) * 513 + it * 32 + 2 * m + kb];
    }
    // W2 swizzled chunk images (linear read, swizzled write); 4 chunks x 128 cols
    {
        int j = tid & 3, kf4 = (tid >> 2) & 15, n = (tid >> 6) & 127, ch = tid >> 13;
        int swz = kf4 ^ ((9 * (n >> 2) + (n & 3)) & 15);
        ws[WS_W2 + ch * WS_W2_CH + n * 64 + swz * 4 + j] = W2[tid];
    }
    if (tid < 64) ws[WS_W1L + tid] = W1[tid * 513 + 512];
}

// ---------------- main fused kernel ----------------
__global__ __launch_bounds__(THREADS, 2) void fused_rgu(
    const float* __restrict__ x, const float* __restrict__ xcons,
    const float* __restrict__ cap, const float* __restrict__ b1,
    const float* __restrict__ b2, const float* __restrict__ ws,
    float* __restrict__ out)
{
    extern __shared__ __align__(16) char smem[];
    float*          s_w    = (float*)(smem + OFF_W);
    float*          s_h1   = (float*)(smem + OFF_H1);
    float*          s_ci   = (float*)(smem + OFF_CI);
    float*          s_b2   = (float*)(smem + OFF_B2);
    float*          s_eps  = (float*)(smem + OFF_EPS);
    float*          s_epsC = (float*)(smem + OFF_EPSC);

    const int t    = threadIdx.x;
    const int lane = t & 63;
    const int wv   = t >> 6;
    const long r0  = (long)blockIdx.x * RPB;

    // stage W1 chunk 0 into buffer 0 early (overlaps the eps phase's global loads)
    {
        const float4* src = (const float4*)(ws + WS_W1);
        float4* dst = (float4*)(smem + OFF_W);
        dst[t] = src[t]; dst[t + 256] = src[t + 256];
    }

    // ---- P0: cap regs, capinv, capSum, b2 stage ----
    float4 capA = *(const float4*)(cap + 4 * lane);
    float4 capB = *(const float4*)(cap + 256 + 4 * lane);
    {
        float c0 = cap[t], c1 = cap[t + 256];
        s_ci[t] = 1.0f / c0; s_ci[t + 256] = 1.0f / c1;
        s_b2[t] = b2[t];     s_b2[t + 256] = b2[t + 256];
    }
    float capSum;
    {
        float p = capA.x + capA.y + capA.z + capA.w
                + capB.x + capB.y + capB.z + capB.w;
        #pragma unroll
        for (int m = 1; m < 64; m <<= 1) p += __shfl_xor(p, m, 64);
        capSum = p;
    }
    const float invCapSum = 1.0f / capSum;

    // ---- P1: epsilon per row (wave wv -> rows wv*8..+7) ----
    #pragma unroll
    for (int rr = 0; rr < 8; ++rr) {
        int r = wv * 8 + rr;
        const float* xr = x + (r0 + r) * 512;
        float4 xA = *(const float4*)(xr + 4 * lane);
        float4 xB = *(const float4*)(xr + 256 + 4 * lane);
        float d = fmaf(xA.x, capA.x, fmaf(xA.y, capA.y,
                  fmaf(xA.z, capA.z, fmaf(xA.w, capA.w,
                  fmaf(xB.x, capB.x, fmaf(xB.y, capB.y,
                  fmaf(xB.z, capB.z, xB.w * capB.w)))))));
        #pragma unroll
        for (int m = 1; m < 64; m <<= 1) d += __shfl_xor(d, m, 64);
        if (lane == 0) {
            float epsC = fmaf(xcons[r0 + r], capSum, -d);   // eps * capSum
            s_epsC[r] = epsC;
            s_eps[r]  = epsC * invCapSum;
        }
    }
    __syncthreads();   // eps/b2/ci visible + W1 chunk 0 staged

    // ---- GEMM1: h1[32][64] = relu(x[32][512] @ W1T + eps*w1last + b1) ----
    // r4 x c2 blocking: t = rg*32 + cg -> rows 4rg..4rg+3, cols 2cg..2cg+1.
    // W-reads HALVED vs r2c4 (256 b128/thread; one b128 = 2k x 2cols via the
    // pair layout); x-reads doubled but ride the separate VMEM pipe (L2-hit).
    const int rg = t >> 5;
    const int cg = t & 31;
    float acc[4][2] = {{0.f,0.f},{0.f,0.f},{0.f,0.f},{0.f,0.f}};
    {
        const float* xg0 = x + (r0 + 4 * rg) * 512;
        const float* xg1 = xg0 + 512;
        const float* xg2 = xg0 + 1024;
        const float* xg3 = xg0 + 1536;
        const int pswz = (cg & 15);
        for (int it = 0; it < 16; ++it) {
            const int b = it & 1;
            if (it < 15) {   // prefetch next chunk into other buffer (no extra barrier)
                const float4* src = (const float4*)(ws + WS_W1 + (it + 1) * WS_W1_CH);
                float4* dst = (float4*)(smem + OFF_W + (b ^ 1) * W1BUF_B);
                dst[t] = src[t]; dst[t + 256] = src[t + 256];
            }
            const float* wp = (const float*)(smem + OFF_W + b * W1BUF_B) + cg * 64;
            const int k0 = it * 32;
            #pragma unroll
            for (int j4 = 0; j4 < 8; ++j4) {
                float4 xv0 = *(const float4*)(xg0 + k0 + j4 * 4);
                float4 xv1 = *(const float4*)(xg1 + k0 + j4 * 4);
                float4 xv2 = *(const float4*)(xg2 + k0 + j4 * 4);
                float4 xv3 = *(const float4*)(xg3 + k0 + j4 * 4);
                // w0 = {k0c0,k0c1,k1c0,k1c1}, w1 = {k2c0,k2c1,k3c0,k3c1}
                float4 w0 = *(const float4*)&wp[((2 * j4)     ^ pswz) << 2];
                float4 w1 = *(const float4*)&wp[((2 * j4 + 1) ^ pswz) << 2];
                #pragma unroll
                for (int i = 0; i < 4; ++i) {
                    float4 xv = (i == 0) ? xv0 : (i == 1) ? xv1 : (i == 2) ? xv2 : xv3;
                    acc[i][0] = fmaf(xv.x, w0.x, fmaf(xv.y, w0.z,
                                fmaf(xv.z, w1.x, fmaf(xv.w, w1.z, acc[i][0]))));
                    acc[i][1] = fmaf(xv.x, w0.y, fmaf(xv.y, w0.w,
                                fmaf(xv.z, w1.y, fmaf(xv.w, w1.w, acc[i][1]))));
                }
            }
            __syncthreads();
        }
        // bias + eps-column + relu in registers, float2 store per row
        float2 b1v = *(const float2*)(b1 + 2 * cg);
        float2 wl  = *(const float2*)(ws + WS_W1L + 2 * cg);
        #pragma unroll
        for (int i = 0; i < 4; ++i) {
            float e = s_eps[4 * rg + i];
            float2 h;
            h.x = fmaxf(acc[i][0] + fmaf(e, wl.x, b1v.x), 0.f);
            h.y = fmaxf(acc[i][1] + fmaf(e, wl.y, b1v.y), 0.f);
            *(float2*)&s_h1[(4 * rg + i) * 68 + 2 * cg] = h;
        }
    }

    // ---- GEMM2 + tanh + rowsum: z[32][512] = h1 @ W2T + b2 ----
    // r4 x c4, 4 chunks of 128 cols (R1's proven shape: 512 ds_reads/thread,
    // h-reads are 2-address broadcasts). t = rg2*32 + ng.
    const int ng  = t & 31;
    const int rg2 = t >> 5;
    float rsum[4] = {0.f, 0.f, 0.f, 0.f};
    unsigned tp[4][4][2];   // 32 VGPRs; ALL indexing static via full unroll
    #pragma unroll
    for (int ch = 0; ch < 4; ++ch) {
        __syncthreads();   // prior users of s_w done (covers h1 stores for ch=0 too)
        {
            const float4* src = (const float4*)(ws + WS_W2 + ch * WS_W2_CH);
            float4* dst = (float4*)(smem + OFF_W);
            #pragma unroll
            for (int e8 = 0; e8 < 8; ++e8) dst[e8 * 256 + t] = src[e8 * 256 + t];
        }
        __syncthreads();
        const int n0 = ch * 128;
        float4 b2v = *(const float4*)&s_b2[n0 + 4 * ng];
        float za[4][4];
        #pragma unroll
        for (int i = 0; i < 4; ++i) {
            za[i][0] = b2v.x; za[i][1] = b2v.y; za[i][2] = b2v.z; za[i][3] = b2v.w;
        }
        #pragma unroll
        for (int kf4 = 0; kf4 < 16; ++kf4) {
            float hr[4][4];
            #pragma unroll
            for (int i = 0; i < 4; ++i) {
                float4 h = *(const float4*)&s_h1[(rg2 * 4 + i) * 68 + kf4 * 4];
                hr[i][0] = h.x; hr[i][1] = h.y; hr[i][2] = h.z; hr[i][3] = h.w;
            }
            float wr2[4][4];
            #pragma unroll
            for (int m = 0; m < 4; ++m) {
                int nl = 4 * ng + m;
                int swz = kf4 ^ ((9 * ng + m) & 15);
                float4 w = *(const float4*)&s_w[nl * 64 + swz * 4];
                wr2[m][0] = w.x; wr2[m][1] = w.y; wr2[m][2] = w.z; wr2[m][3] = w.w;
            }
            #pragma unroll
            for (int i = 0; i < 4; ++i)
                #pragma unroll
                for (int m = 0; m < 4; ++m)
                    za[i][m] = fmaf(hr[i][0], wr2[m][0], fmaf(hr[i][1], wr2[m][1],
                               fmaf(hr[i][2], wr2[m][2], fmaf(hr[i][3], wr2[m][3], za[i][m]))));
        }
        #pragma unroll
        for (int i = 0; i < 4; ++i) {
            float t0 = fast_tanh(za[i][0]);
            float t1 = fast_tanh(za[i][1]);
            float t2 = fast_tanh(za[i][2]);
            float t3 = fast_tanh(za[i][3]);
            rsum[i] += (t0 + t1) + (t2 + t3);
            __half2 h01 = __floats2half2_rn(t0, t1);
            __half2 h23 = __floats2half2_rn(t2, t3);
            tp[ch][i][0] = *(unsigned*)&h01;
            tp[ch][i][1] = *(unsigned*)&h23;
        }
    }

    // reduce rowsums across the 32 ng lanes (within wave halves); every lane
    // ends up holding S for its rows -> rs in-register, no LDS, no barrier.
    float rs[4];
    #pragma unroll
    for (int i = 0; i < 4; ++i) {
        float s = rsum[i];
        #pragma unroll
        for (int msk = 1; msk < 32; msk <<= 1) s += __shfl_xor(s, msk, 64);
        rs[i] = s_epsC[rg2 * 4 + i] / s;   // eps*capSum / S
    }

    // ---- epilogue (fused, per-thread): out = x + t * (epsC/S) * capinv ----
    // For fixed (ch,i) a wave-half writes 512 B contiguous -> coalesced.
    #pragma unroll
    for (int ch = 0; ch < 4; ++ch) {
        const int c = ch * 128 + 4 * ng;
        float4 ci = *(const float4*)&s_ci[c];
        #pragma unroll
        for (int i = 0; i < 4; ++i) {
            const int r = rg2 * 4 + i;
            float4 xv = *(const float4*)(x + (r0 + r) * 512 + c);
            __half2 h01 = *(__half2*)&tp[ch][i][0];
            __half2 h23 = *(__half2*)&tp[ch][i][1];
            float2 f01 = __half22float2(h01);
            float2 f23 = __half22float2(h23);
            float ri = rs[i];
            float4 o;
            o.x = fmaf(f01.x, ri * ci.x, xv.x);
            o.y = fmaf(f01.y, ri * ci.y, xv.y);
            o.z = fmaf(f23.x, ri * ci.z, xv.z);
            o.w = fmaf(f23.y, ri * ci.w, xv.w);
            *(float4*)(out + (r0 + r) * 512 + c) = o;
        }
    }
}

extern "C" void kernel_launch(void* const* d_in, const int* in_sizes, int n_in,
                              void* d_out, int out_size, void* d_ws, size_t ws_size,
                              hipStream_t stream) {
    const float* x     = (const float*)d_in[0];
    const float* xcons = (const float*)d_in[1];
    const float* cap   = (const float*)d_in[2];
    const float* W1    = (const float*)d_in[3];
    const float* b1    = (const float*)d_in[4];
    const float* W2    = (const float*)d_in[5];
    const float* b2    = (const float*)d_in[6];
    float* out         = (float*)d_out;
    float* ws          = (float*)d_ws;

    (void)in_sizes; (void)n_in; (void)out_size; (void)ws_size;

    prep_kernel<<<128, 256, 0, stream>>>(W1, W2, ws);

    hipFuncSetAttribute((const void*)fused_rgu,
                        hipFuncAttributeMaxDynamicSharedMemorySize, SMEM_BYTES);
    fused_rgu<<<NBLK, THREADS, SMEM_BYTES, stream>>>(
        x, xcons, cap, b1, b2, ws, out);
}